// Round 12
// baseline (118.102 us; speedup 1.0000x reference)
//
#include <hip/hip_runtime.h>

typedef __bf16 bf16_t;
typedef bf16_t bf16x8 __attribute__((ext_vector_type(8)));
typedef float f32x4 __attribute__((ext_vector_type(4)));
typedef unsigned short ushort8 __attribute__((ext_vector_type(8)));

#define LOG2E 1.4426950408889634f

static __device__ __forceinline__ unsigned short f2bf(float f) {
  union { float f; unsigned u; } a; a.f = f;
  unsigned r = a.u + 0x7FFFu + ((a.u >> 16) & 1u);
  return (unsigned short)(r >> 16);
}

static __device__ __forceinline__ bf16x8 ldb8(const unsigned short* p) {
  return *reinterpret_cast<const bf16x8*>(p);
}

// ---------------- kernel 1: Q/K/V projections, self-staged weights (r10-proven) ----
__global__ __launch_bounds__(256) void proj_k(
    const float* __restrict__ X, const float* __restrict__ bq,
    const float* __restrict__ Wq, const float* __restrict__ Wk,
    const float* __restrict__ Wv,
    unsigned short* __restrict__ q_ws, unsigned short* __restrict__ k_ws,
    unsigned short* __restrict__ vt_ws) {
  __shared__ unsigned short wl[64][264];
  __shared__ unsigned short vtile[64][72];
  const int tid = threadIdx.x;
  const int wave = tid >> 6, l = tid & 63, g = l >> 4, l15 = l & 15;
  const int mrow = blockIdx.x * 64 + wave * 16 + l15;  // A-fragment row
  const int widx = blockIdx.y >> 2;                    // 0=Wq 1=Wk 2=Wv
  const int nin0 = (blockIdx.y & 3) * 64;              // col within weight
  const float* W = (widx == 0) ? Wq : (widx == 1) ? Wk : Wv;

  {
    const int c = tid & 63;
#pragma unroll
    for (int kk = tid >> 6; kk < 256; kk += 4)
      wl[c][kk] = f2bf(W[kk * 256 + nin0 + c]);
  }
  __syncthreads();

  f32x4 acc[4];
#pragma unroll
  for (int st = 0; st < 4; ++st) acc[st] = f32x4{0.f, 0.f, 0.f, 0.f};

#pragma unroll
  for (int kk0 = 0; kk0 < 256; kk0 += 32) {
    const float* xp = X + mrow * 256 + kk0 + 8 * g;
    f32x4 x0 = *reinterpret_cast<const f32x4*>(xp);
    f32x4 x1 = *reinterpret_cast<const f32x4*>(xp + 4);
    union { unsigned short u[8]; bf16x8 v; } av;
#pragma unroll
    for (int e = 0; e < 4; ++e) { av.u[e] = f2bf(x0[e]); av.u[4 + e] = f2bf(x1[e]); }
#pragma unroll
    for (int st = 0; st < 4; ++st) {
      bf16x8 bv = ldb8(&wl[st * 16 + l15][kk0 + 8 * g]);
      acc[st] = __builtin_amdgcn_mfma_f32_16x16x32_bf16(av.v, bv, acc[st], 0, 0, 0);
    }
  }

  const int mb = blockIdx.x * 64 + wave * 16 + 4 * g;  // D rows = 4g+j
  if (widx == 2) {
#pragma unroll
    for (int st = 0; st < 4; ++st)
#pragma unroll
      for (int j = 0; j < 4; ++j)
        vtile[st * 16 + l15][wave * 16 + 4 * g + j] = f2bf(acc[st][j]);
    __syncthreads();
    const int b = (blockIdx.x * 64) >> 11;
    const int t0 = (blockIdx.x * 64) & 2047;
#pragma unroll
    for (int it = tid; it < 512; it += 256) {
      const int r = it >> 3, cseg = (it & 7) * 8;
      const int n = nin0 + r;
      *reinterpret_cast<ushort8*>(vt_ws + (size_t)((b * 8 + (n >> 5)) * 32 + (n & 31)) * 2048 +
                                  t0 + cseg) = *reinterpret_cast<const ushort8*>(&vtile[r][cseg]);
    }
  } else {
#pragma unroll
    for (int st = 0; st < 4; ++st) {
      const int n = nin0 + st * 16 + l15;
      const int h = n >> 5, d = n & 31;
#pragma unroll
      for (int j = 0; j < 4; ++j) {
        const int m = mb + j;
        const int b = m >> 11, t = m & 2047;
        if (widx == 0) {
          q_ws[((b * 8 + h) * 2048 + t) * 32 + d] =
              f2bf((acc[st][j] + bq[n]) * (0.17677669529663687f * LOG2E));
        } else {
          k_ws[((b * 8 + h) * 2048 + t) * 32 + d] = f2bf(acc[st][j]);
        }
      }
    }
  }
}

// ------- kernel 2: flash attention, key-split x2 at 12 waves/CU (no spill) --------
// r10's byte-equal pipeline (LDS bias dbuf + separate plds, 41 KB) with the key
// dim split across 2 blocks. __launch_bounds__(256,3): VGPR cap 170 (live ~130,
// cannot spill), 3 blocks/CU resident = 12 waves/CU = 1.5x bias DMA in-flight.
// No XCD swizzle, no P-overlay (r11's confounds removed).
__global__ __launch_bounds__(256, 3) void attn_k(
    const unsigned short* __restrict__ q_ws, const unsigned short* __restrict__ k_ws,
    const unsigned short* __restrict__ vt_ws, const float* __restrict__ bias,
    float* __restrict__ p_o, float* __restrict__ p_ml) {
  __shared__ float sbias[4][2][1024];           // 32 KB
  __shared__ unsigned short plds[4][16 * 72];   // 9 KB
  const int tid = threadIdx.x;
  const int wave = tid >> 6, l = tid & 63, g = l >> 4, l15 = l & 15;
  const int bid = blockIdx.x;
  const int bh = bid >> 6;
  const int qt = (bid & 63) >> 1;
  const int split = bid & 1;
  const int koff = split << 10;  // 1024 keys per split
  const int qr0 = qt * 64 + wave * 16;
  const int kvbase = bh * 2048;
  unsigned short* pw = plds[wave];

  const bf16x8 qa = ldb8(q_ws + (size_t)(kvbase + qr0 + l15) * 32 + 8 * g);
  const unsigned short* kbase = k_ws + (size_t)kvbase * 32 + 8 * g + l15 * 32;
  const unsigned short* vbase = vt_ws + (size_t)(bh * 32 + l15) * 2048 + 8 * g;
  // per-lane staging source: lane l covers row (l>>4) of each 4-row group, 16B at col (l&15)*4
  const float* bsrc = bias + ((size_t)bh << 22) + (size_t)(qr0 + (l >> 4)) * 2048 + (l & 15) * 4;

  auto stage = [&](int buf, int k0) {
    float* dst = &sbias[wave][buf][0];
#pragma unroll
    for (int qq = 0; qq < 4; ++qq)
      __builtin_amdgcn_global_load_lds(
          (const __attribute__((address_space(1))) void*)(bsrc + (size_t)qq * 8192 + k0),
          (__attribute__((address_space(3))) void*)(dst + qq * 256), 16, 0, 0);
  };

  float mr[4], lr[4];
  f32x4 oacc[2];
#pragma unroll
  for (int j = 0; j < 4; ++j) { mr[j] = -1e30f; lr[j] = 0.0f; }
  oacc[0] = f32x4{0.f, 0.f, 0.f, 0.f};
  oacc[1] = f32x4{0.f, 0.f, 0.f, 0.f};

  stage(0, koff);
#pragma unroll 1
  for (int kt = 0; kt < 16; ++kt) {
    const int buf = kt & 1;
    const int k0 = koff + kt * 64;
    // only outstanding vmem here = stage(kt) -> drain exactly it
    asm volatile("s_waitcnt vmcnt(0)" ::: "memory");
    __builtin_amdgcn_sched_barrier(0);
    // bias fragments (C-operand layout) from LDS buffer buf
    f32x4 cfr[4];
    const float* sbc = &sbias[wave][buf][0] + l15;
#pragma unroll
    for (int st = 0; st < 4; ++st)
#pragma unroll
      for (int j = 0; j < 4; ++j)
        cfr[st][j] = sbc[(4 * g + j) * 64 + st * 16] * LOG2E;

    // K/V fragment loads for this tile (issued BEFORE next staging)
    bf16x8 kb[4];
#pragma unroll
    for (int st = 0; st < 4; ++st) kb[st] = ldb8(kbase + (size_t)(k0 + st * 16) * 32);
    bf16x8 vb[2][2];
#pragma unroll
    for (int dst = 0; dst < 2; ++dst)
#pragma unroll
      for (int kc = 0; kc < 2; ++kc)
        vb[dst][kc] = ldb8(vbase + (size_t)dst * 16 * 2048 + k0 + kc * 32);

    // issue stage(kt+1) into the other buffer (newest vmem)
    if (kt < 15) stage(buf ^ 1, k0 + 64);

    // S = QK^T + bias (bias as MFMA C-operand), base-2 domain
    f32x4 s[4];
#pragma unroll
    for (int st = 0; st < 4; ++st)
      s[st] = __builtin_amdgcn_mfma_f32_16x16x32_bf16(qa, kb[st], cfr[st], 0, 0, 0);

    // online softmax per row (row = 4g+j)
#pragma unroll
    for (int j = 0; j < 4; ++j) {
      float mx = fmaxf(fmaxf(s[0][j], s[1][j]), fmaxf(s[2][j], s[3][j]));
      mx = fmaxf(mx, __shfl_xor(mx, 1));
      mx = fmaxf(mx, __shfl_xor(mx, 2));
      mx = fmaxf(mx, __shfl_xor(mx, 4));
      mx = fmaxf(mx, __shfl_xor(mx, 8));
      const float mn = fmaxf(mr[j], mx);
      const float sc = __builtin_amdgcn_exp2f(mr[j] - mn);
      mr[j] = mn;
      float rs = 0.f;
#pragma unroll
      for (int st = 0; st < 4; ++st) {
        float e = __builtin_amdgcn_exp2f(s[st][j] - mn);
        s[st][j] = e;
        rs += e;
      }
      rs += __shfl_xor(rs, 1);
      rs += __shfl_xor(rs, 2);
      rs += __shfl_xor(rs, 4);
      rs += __shfl_xor(rs, 8);
      lr[j] = lr[j] * sc + rs;
      oacc[0][j] *= sc;
      oacc[1][j] *= sc;
    }
    // P -> LDS (transpose to A-fragment layout); per-wave buffer, DS in-order
#pragma unroll
    for (int st = 0; st < 4; ++st)
#pragma unroll
      for (int j = 0; j < 4; ++j)
        pw[(4 * g + j) * 72 + st * 16 + l15] = f2bf(s[st][j]);
#pragma unroll
    for (int kc = 0; kc < 2; ++kc) {
      bf16x8 pa = ldb8(pw + l15 * 72 + kc * 32 + 8 * g);
      oacc[0] = __builtin_amdgcn_mfma_f32_16x16x32_bf16(pa, vb[0][kc], oacc[0], 0, 0, 0);
      oacc[1] = __builtin_amdgcn_mfma_f32_16x16x32_bf16(pa, vb[1][kc], oacc[1], 0, 0, 0);
    }
  }

  // write unnormalized partials + (m,l) for this split
  const int rowbase = kvbase + qr0;
  float* po = p_o + ((size_t)split * 32768 + rowbase) * 32;
#pragma unroll
  for (int dst = 0; dst < 2; ++dst)
#pragma unroll
    for (int j = 0; j < 4; ++j)
      po[(4 * g + j) * 32 + dst * 16 + l15] = oacc[dst][j];
  if (l15 == 0) {
#pragma unroll
    for (int j = 0; j < 4; ++j) {
      const size_t r = (size_t)split * 32768 + rowbase + 4 * g + j;
      p_ml[r * 2] = mr[j];
      p_ml[r * 2 + 1] = lr[j];
    }
  }
}

// ---------------- kernel 2b: merge the two key-splits (exact, base-2 domain) ----
__global__ __launch_bounds__(256) void combine_k(
    const float* __restrict__ p_o, const float* __restrict__ p_ml,
    unsigned short* __restrict__ o_ws) {
  const int gid = blockIdx.x * 256 + threadIdx.x;  // 0 .. 1M-1
  const int row = gid >> 5, d = gid & 31;
  const float m0 = p_ml[row * 2], l0 = p_ml[row * 2 + 1];
  const float m1 = p_ml[(32768 + row) * 2], l1 = p_ml[(32768 + row) * 2 + 1];
  const float m = fmaxf(m0, m1);
  const float w0 = __builtin_amdgcn_exp2f(m0 - m), w1 = __builtin_amdgcn_exp2f(m1 - m);
  const float o0 = p_o[(size_t)row * 32 + d];
  const float o1 = p_o[(size_t)(32768 + row) * 32 + d];
  const float val = (o0 * w0 + o1 * w1) / (l0 * w0 + l1 * w1);
  const int bh = row >> 11, q = row & 2047;
  const int b = bh >> 3, h = bh & 7;
  o_ws[((size_t)(b * 2048 + q)) * 256 + h * 32 + d] = f2bf(val);
}

// ------- kernel 3: out = sigmoid(x@Wg + bg + gbias) * (o@Wout + bout) (r10-proven) -
__global__ __launch_bounds__(256) void outp_k(
    const unsigned short* __restrict__ o_ws, const float* __restrict__ X,
    const float* __restrict__ Wg, const float* __restrict__ Wo,
    const float* __restrict__ bout, const float* __restrict__ bg,
    const float* __restrict__ gbias, float* __restrict__ out) {
  __shared__ unsigned short wgl[64][264];
  __shared__ unsigned short wol[64][264];
  const int tid = threadIdx.x;
  const int wave = tid >> 6, l = tid & 63, g = l >> 4, l15 = l & 15;
  const int m0 = blockIdx.x * 64 + wave * 16;
  const int c0 = blockIdx.y * 64;

  {
    const int c = tid & 63;
#pragma unroll
    for (int kk = tid >> 6; kk < 256; kk += 4) {
      wgl[c][kk] = f2bf(Wg[kk * 256 + c0 + c]);
      wol[c][kk] = f2bf(Wo[kk * 256 + c0 + c]);
    }
  }
  __syncthreads();

  f32x4 acco[4], accg[4];
#pragma unroll
  for (int st = 0; st < 4; ++st) {
    acco[st] = f32x4{0.f, 0.f, 0.f, 0.f};
    accg[st] = f32x4{0.f, 0.f, 0.f, 0.f};
  }
#pragma unroll
  for (int kk0 = 0; kk0 < 256; kk0 += 32) {
    const bf16x8 a_o = ldb8(o_ws + (m0 + l15) * 256 + kk0 + 8 * g);
    const float* xp = X + (m0 + l15) * 256 + kk0 + 8 * g;
    f32x4 x0 = *reinterpret_cast<const f32x4*>(xp);
    f32x4 x1 = *reinterpret_cast<const f32x4*>(xp + 4);
    union { unsigned short u[8]; bf16x8 v; } av;
#pragma unroll
    for (int e = 0; e < 4; ++e) { av.u[e] = f2bf(x0[e]); av.u[4 + e] = f2bf(x1[e]); }
#pragma unroll
    for (int st = 0; st < 4; ++st) {
      bf16x8 bo = ldb8(&wol[st * 16 + l15][kk0 + 8 * g]);
      acco[st] = __builtin_amdgcn_mfma_f32_16x16x32_bf16(a_o, bo, acco[st], 0, 0, 0);
      bf16x8 bgf = ldb8(&wgl[st * 16 + l15][kk0 + 8 * g]);
      accg[st] = __builtin_amdgcn_mfma_f32_16x16x32_bf16(av.v, bgf, accg[st], 0, 0, 0);
    }
  }
  const int mb = m0 + 4 * g;
#pragma unroll
  for (int st = 0; st < 4; ++st) {
    const int n = c0 + st * 16 + l15;
#pragma unroll
    for (int j = 0; j < 4; ++j) {
      const int m = mb + j;
      const float z = accg[st][j] + bg[n] + gbias[n];
      const float gate = 1.0f / (1.0f + __expf(-z));
      out[m * 256 + n] = gate * (acco[st][j] + bout[n]);
    }
  }
}

extern "C" void kernel_launch(void* const* d_in, const int* in_sizes, int n_in,
                              void* d_out, int out_size, void* d_ws, size_t ws_size,
                              hipStream_t stream) {
  const float* q_x   = (const float*)d_in[0];
  const float* bias  = (const float*)d_in[1];
  const float* Wq    = (const float*)d_in[2];
  const float* bq    = (const float*)d_in[3];
  const float* Wk    = (const float*)d_in[4];
  const float* Wv    = (const float*)d_in[5];
  const float* Wout  = (const float*)d_in[6];
  const float* bout  = (const float*)d_in[7];
  const float* Wg    = (const float*)d_in[8];
  const float* bg    = (const float*)d_in[9];
  const float* gbias = (const float*)d_in[10];
  float* out = (float*)d_out;

  char* ws = (char*)d_ws;
  unsigned short* q_ws  = (unsigned short*)(ws);                 // 2 MB
  unsigned short* k_ws  = (unsigned short*)(ws + 2097152);       // 2 MB
  unsigned short* vt_ws = (unsigned short*)(ws + 2 * 2097152);   // 2 MB
  unsigned short* o_ws  = (unsigned short*)(ws + 3 * 2097152);   // 2 MB
  float* p_o            = (float*)(ws + 4 * 2097152);            // 8 MB
  float* p_ml           = (float*)(ws + 8 * 2097152);            // 512 KB

  proj_k<<<dim3(64, 12), 256, 0, stream>>>(q_x, bq, Wq, Wk, Wv, q_ws, k_ws, vt_ws);
  attn_k<<<1024, 256, 0, stream>>>(q_ws, k_ws, vt_ws, bias, p_o, p_ml);
  combine_k<<<4096, 256, 0, stream>>>(p_o, p_ml, o_ws);
  outp_k<<<dim3(64, 4), 256, 0, stream>>>(o_ws, q_x, Wg, Wout, bout, bg, gbias, out);
}

// Round 13
// 94.983 us; speedup vs baseline: 1.2434x; 1.2434x over previous
//
#include <hip/hip_runtime.h>

typedef __bf16 bf16_t;
typedef bf16_t bf16x8 __attribute__((ext_vector_type(8)));
typedef float f32x4 __attribute__((ext_vector_type(4)));
typedef unsigned short ushort8 __attribute__((ext_vector_type(8)));

#define LOG2E 1.4426950408889634f

static __device__ __forceinline__ unsigned short f2bf(float f) {
  union { float f; unsigned u; } a; a.f = f;
  unsigned r = a.u + 0x7FFFu + ((a.u >> 16) & 1u);
  return (unsigned short)(r >> 16);
}

static __device__ __forceinline__ bf16x8 ldb8(const unsigned short* p) {
  return *reinterpret_cast<const bf16x8*>(p);
}

// ---------------- kernel 1: Q/K/V projections, self-staged weights (r10-proven) ----
__global__ __launch_bounds__(256) void proj_k(
    const float* __restrict__ X, const float* __restrict__ bq,
    const float* __restrict__ Wq, const float* __restrict__ Wk,
    const float* __restrict__ Wv,
    unsigned short* __restrict__ q_ws, unsigned short* __restrict__ k_ws,
    unsigned short* __restrict__ vt_ws) {
  __shared__ unsigned short wl[64][264];
  __shared__ unsigned short vtile[64][72];
  const int tid = threadIdx.x;
  const int wave = tid >> 6, l = tid & 63, g = l >> 4, l15 = l & 15;
  const int mrow = blockIdx.x * 64 + wave * 16 + l15;  // A-fragment row
  const int widx = blockIdx.y >> 2;                    // 0=Wq 1=Wk 2=Wv
  const int nin0 = (blockIdx.y & 3) * 64;              // col within weight
  const float* W = (widx == 0) ? Wq : (widx == 1) ? Wk : Wv;

  {
    const int c = tid & 63;
#pragma unroll
    for (int kk = tid >> 6; kk < 256; kk += 4)
      wl[c][kk] = f2bf(W[kk * 256 + nin0 + c]);
  }
  __syncthreads();

  f32x4 acc[4];
#pragma unroll
  for (int st = 0; st < 4; ++st) acc[st] = f32x4{0.f, 0.f, 0.f, 0.f};

#pragma unroll
  for (int kk0 = 0; kk0 < 256; kk0 += 32) {
    const float* xp = X + mrow * 256 + kk0 + 8 * g;
    f32x4 x0 = *reinterpret_cast<const f32x4*>(xp);
    f32x4 x1 = *reinterpret_cast<const f32x4*>(xp + 4);
    union { unsigned short u[8]; bf16x8 v; } av;
#pragma unroll
    for (int e = 0; e < 4; ++e) { av.u[e] = f2bf(x0[e]); av.u[4 + e] = f2bf(x1[e]); }
#pragma unroll
    for (int st = 0; st < 4; ++st) {
      bf16x8 bv = ldb8(&wl[st * 16 + l15][kk0 + 8 * g]);
      acc[st] = __builtin_amdgcn_mfma_f32_16x16x32_bf16(av.v, bv, acc[st], 0, 0, 0);
    }
  }

  const int mb = blockIdx.x * 64 + wave * 16 + 4 * g;  // D rows = 4g+j
  if (widx == 2) {
#pragma unroll
    for (int st = 0; st < 4; ++st)
#pragma unroll
      for (int j = 0; j < 4; ++j)
        vtile[st * 16 + l15][wave * 16 + 4 * g + j] = f2bf(acc[st][j]);
    __syncthreads();
    const int b = (blockIdx.x * 64) >> 11;
    const int t0 = (blockIdx.x * 64) & 2047;
#pragma unroll
    for (int it = tid; it < 512; it += 256) {
      const int r = it >> 3, cseg = (it & 7) * 8;
      const int n = nin0 + r;
      *reinterpret_cast<ushort8*>(vt_ws + (size_t)((b * 8 + (n >> 5)) * 32 + (n & 31)) * 2048 +
                                  t0 + cseg) = *reinterpret_cast<const ushort8*>(&vtile[r][cseg]);
    }
  } else {
#pragma unroll
    for (int st = 0; st < 4; ++st) {
      const int n = nin0 + st * 16 + l15;
      const int h = n >> 5, d = n & 31;
#pragma unroll
      for (int j = 0; j < 4; ++j) {
        const int m = mb + j;
        const int b = m >> 11, t = m & 2047;
        if (widx == 0) {
          q_ws[((b * 8 + h) * 2048 + t) * 32 + d] =
              f2bf((acc[st][j] + bq[n]) * (0.17677669529663687f * LOG2E));
        } else {
          k_ws[((b * 8 + h) * 2048 + t) * 32 + d] = f2bf(acc[st][j]);
        }
      }
    }
  }
}

// ---------------- kernel 2: flash attention (r10 pipeline) + XCD-bijective swizzle ----
// Single change vs r10: block remap nb = (bid&7)*64 + (bid>>3) so each XCD owns
// 2 COMPLETE bh groups (64 blocks). Same-bh blocks co-run on one XCD -> each K/V
// tile (4 KB) is re-used by 32 blocks within the per-XCD L2 residency window
// (~8 us vs ~2 us tile skew), converting ~128 MB of K/V HBM re-fetch into L2 hits.
// Pipeline, LDS (41 KB), VGPR budget, vmcnt discipline byte-identical to r10.
__global__ __launch_bounds__(256, 3) void attn_k(
    const unsigned short* __restrict__ q_ws, const unsigned short* __restrict__ k_ws,
    const unsigned short* __restrict__ vt_ws, const float* __restrict__ bias,
    unsigned short* __restrict__ o_ws) {
  __shared__ float sbias[4][2][1024];           // [wave][2 bufs][16*64] = 32 KB
  __shared__ unsigned short plds[4][16 * 72];   // 9 KB per-wave P buffers
  const int tid = threadIdx.x;
  const int wave = tid >> 6, l = tid & 63, g = l >> 4, l15 = l & 15;
  // XCD-bijective swizzle: XCD x (= bid%8, round-robin dispatch) gets nb in
  // [x*64, x*64+64) = bh {2x, 2x+1} complete.
  const int bid = blockIdx.x;
  const int nb = (bid & 7) * 64 + (bid >> 3);
  const int bh = nb >> 5, qt = nb & 31;
  const int qr0 = qt * 64 + wave * 16;
  const int kvbase = bh * 2048;
  unsigned short* pw = plds[wave];

  const bf16x8 qa = ldb8(q_ws + (size_t)(kvbase + qr0 + l15) * 32 + 8 * g);
  const unsigned short* kbase = k_ws + (size_t)kvbase * 32 + 8 * g + l15 * 32;
  const unsigned short* vbase = vt_ws + (size_t)(bh * 32 + l15) * 2048 + 8 * g;
  // per-lane staging source: lane l covers row (l>>4) of each 4-row group, 16B at col (l&15)*4
  const float* bsrc = bias + ((size_t)bh << 22) + (size_t)(qr0 + (l >> 4)) * 2048 + (l & 15) * 4;

  // stage 64-key tile with key-offset k0 into LDS buffer buf (4 x 1KB instrs)
  auto stage = [&](int buf, int k0) {
    float* dst = &sbias[wave][buf][0];
#pragma unroll
    for (int qq = 0; qq < 4; ++qq)
      __builtin_amdgcn_global_load_lds(
          (const __attribute__((address_space(1))) void*)(bsrc + (size_t)qq * 8192 + k0),
          (__attribute__((address_space(3))) void*)(dst + qq * 256), 16, 0, 0);
  };

  float mr[4], lr[4];
  f32x4 oacc[2];
#pragma unroll
  for (int j = 0; j < 4; ++j) { mr[j] = -1e30f; lr[j] = 0.0f; }
  oacc[0] = f32x4{0.f, 0.f, 0.f, 0.f};
  oacc[1] = f32x4{0.f, 0.f, 0.f, 0.f};

  stage(0, 0);
#pragma unroll 1
  for (int kt = 0; kt < 32; ++kt) {
    const int buf = kt & 1;
    const int k0 = kt * 64;
    // only outstanding vmem here = stage(kt) -> drain exactly it
    asm volatile("s_waitcnt vmcnt(0)" ::: "memory");
    __builtin_amdgcn_sched_barrier(0);
    // bias fragments (C-operand layout) from LDS buffer buf
    f32x4 cfr[4];
    const float* sbc = &sbias[wave][buf][0] + l15;
#pragma unroll
    for (int st = 0; st < 4; ++st)
#pragma unroll
      for (int j = 0; j < 4; ++j)
        cfr[st][j] = sbc[(4 * g + j) * 64 + st * 16] * LOG2E;

    // K/V fragment loads for this tile (issued BEFORE next staging)
    bf16x8 kb[4];
#pragma unroll
    for (int st = 0; st < 4; ++st) kb[st] = ldb8(kbase + (size_t)(k0 + st * 16) * 32);
    bf16x8 vb[2][2];
#pragma unroll
    for (int dst = 0; dst < 2; ++dst)
#pragma unroll
      for (int kc = 0; kc < 2; ++kc)
        vb[dst][kc] = ldb8(vbase + (size_t)dst * 16 * 2048 + k0 + kc * 32);

    // issue stage(kt+1) into the other buffer (newest vmem)
    if (kt < 31) stage(buf ^ 1, k0 + 64);

    // S = QK^T + bias (bias as MFMA C-operand), base-2 domain
    f32x4 s[4];
#pragma unroll
    for (int st = 0; st < 4; ++st)
      s[st] = __builtin_amdgcn_mfma_f32_16x16x32_bf16(qa, kb[st], cfr[st], 0, 0, 0);

    // online softmax per row (row = 4g+j)
#pragma unroll
    for (int j = 0; j < 4; ++j) {
      float mx = fmaxf(fmaxf(s[0][j], s[1][j]), fmaxf(s[2][j], s[3][j]));
      mx = fmaxf(mx, __shfl_xor(mx, 1));
      mx = fmaxf(mx, __shfl_xor(mx, 2));
      mx = fmaxf(mx, __shfl_xor(mx, 4));
      mx = fmaxf(mx, __shfl_xor(mx, 8));
      const float mn = fmaxf(mr[j], mx);
      const float sc = __builtin_amdgcn_exp2f(mr[j] - mn);
      mr[j] = mn;
      float rs = 0.f;
#pragma unroll
      for (int st = 0; st < 4; ++st) {
        float e = __builtin_amdgcn_exp2f(s[st][j] - mn);
        s[st][j] = e;
        rs += e;
      }
      rs += __shfl_xor(rs, 1);
      rs += __shfl_xor(rs, 2);
      rs += __shfl_xor(rs, 4);
      rs += __shfl_xor(rs, 8);
      lr[j] = lr[j] * sc + rs;
      oacc[0][j] *= sc;
      oacc[1][j] *= sc;
    }
    // P -> LDS (transpose to A-fragment layout); per-wave buffer, DS in-order
#pragma unroll
    for (int st = 0; st < 4; ++st)
#pragma unroll
      for (int j = 0; j < 4; ++j)
        pw[(4 * g + j) * 72 + st * 16 + l15] = f2bf(s[st][j]);
#pragma unroll
    for (int kc = 0; kc < 2; ++kc) {
      bf16x8 pa = ldb8(pw + l15 * 72 + kc * 32 + 8 * g);
      oacc[0] = __builtin_amdgcn_mfma_f32_16x16x32_bf16(pa, vb[0][kc], oacc[0], 0, 0, 0);
      oacc[1] = __builtin_amdgcn_mfma_f32_16x16x32_bf16(pa, vb[1][kc], oacc[1], 0, 0, 0);
    }
  }

  const int b = bh >> 3, h = bh & 7;
#pragma unroll
  for (int dst = 0; dst < 2; ++dst)
#pragma unroll
    for (int j = 0; j < 4; ++j) {
      const int q = qr0 + 4 * g + j;
      const float val = oacc[dst][j] / lr[j];
      o_ws[((size_t)(b * 2048 + q)) * 256 + h * 32 + dst * 16 + l15] = f2bf(val);
    }
}

// ------- kernel 3: out = sigmoid(x@Wg + bg + gbias) * (o@Wout + bout) (r10-proven) -
__global__ __launch_bounds__(256) void outp_k(
    const unsigned short* __restrict__ o_ws, const float* __restrict__ X,
    const float* __restrict__ Wg, const float* __restrict__ Wo,
    const float* __restrict__ bout, const float* __restrict__ bg,
    const float* __restrict__ gbias, float* __restrict__ out) {
  __shared__ unsigned short wgl[64][264];
  __shared__ unsigned short wol[64][264];
  const int tid = threadIdx.x;
  const int wave = tid >> 6, l = tid & 63, g = l >> 4, l15 = l & 15;
  const int m0 = blockIdx.x * 64 + wave * 16;
  const int c0 = blockIdx.y * 64;

  {
    const int c = tid & 63;
#pragma unroll
    for (int kk = tid >> 6; kk < 256; kk += 4) {
      wgl[c][kk] = f2bf(Wg[kk * 256 + c0 + c]);
      wol[c][kk] = f2bf(Wo[kk * 256 + c0 + c]);
    }
  }
  __syncthreads();

  f32x4 acco[4], accg[4];
#pragma unroll
  for (int st = 0; st < 4; ++st) {
    acco[st] = f32x4{0.f, 0.f, 0.f, 0.f};
    accg[st] = f32x4{0.f, 0.f, 0.f, 0.f};
  }
#pragma unroll
  for (int kk0 = 0; kk0 < 256; kk0 += 32) {
    const bf16x8 a_o = ldb8(o_ws + (m0 + l15) * 256 + kk0 + 8 * g);
    const float* xp = X + (m0 + l15) * 256 + kk0 + 8 * g;
    f32x4 x0 = *reinterpret_cast<const f32x4*>(xp);
    f32x4 x1 = *reinterpret_cast<const f32x4*>(xp + 4);
    union { unsigned short u[8]; bf16x8 v; } av;
#pragma unroll
    for (int e = 0; e < 4; ++e) { av.u[e] = f2bf(x0[e]); av.u[4 + e] = f2bf(x1[e]); }
#pragma unroll
    for (int st = 0; st < 4; ++st) {
      bf16x8 bo = ldb8(&wol[st * 16 + l15][kk0 + 8 * g]);
      acco[st] = __builtin_amdgcn_mfma_f32_16x16x32_bf16(a_o, bo, acco[st], 0, 0, 0);
      bf16x8 bgf = ldb8(&wgl[st * 16 + l15][kk0 + 8 * g]);
      accg[st] = __builtin_amdgcn_mfma_f32_16x16x32_bf16(av.v, bgf, accg[st], 0, 0, 0);
    }
  }
  const int mb = m0 + 4 * g;
#pragma unroll
  for (int st = 0; st < 4; ++st) {
    const int n = c0 + st * 16 + l15;
#pragma unroll
    for (int j = 0; j < 4; ++j) {
      const int m = mb + j;
      const float z = accg[st][j] + bg[n] + gbias[n];
      const float gate = 1.0f / (1.0f + __expf(-z));
      out[m * 256 + n] = gate * (acco[st][j] + bout[n]);
    }
  }
}

extern "C" void kernel_launch(void* const* d_in, const int* in_sizes, int n_in,
                              void* d_out, int out_size, void* d_ws, size_t ws_size,
                              hipStream_t stream) {
  const float* q_x   = (const float*)d_in[0];
  const float* bias  = (const float*)d_in[1];
  const float* Wq    = (const float*)d_in[2];
  const float* bq    = (const float*)d_in[3];
  const float* Wk    = (const float*)d_in[4];
  const float* Wv    = (const float*)d_in[5];
  const float* Wout  = (const float*)d_in[6];
  const float* bout  = (const float*)d_in[7];
  const float* Wg    = (const float*)d_in[8];
  const float* bg    = (const float*)d_in[9];
  const float* gbias = (const float*)d_in[10];
  float* out = (float*)d_out;

  char* ws = (char*)d_ws;
  unsigned short* q_ws  = (unsigned short*)(ws);                 // 2 MB
  unsigned short* k_ws  = (unsigned short*)(ws + 2097152);       // 2 MB
  unsigned short* vt_ws = (unsigned short*)(ws + 2 * 2097152);   // 2 MB
  unsigned short* o_ws  = (unsigned short*)(ws + 3 * 2097152);   // 2 MB

  proj_k<<<dim3(64, 12), 256, 0, stream>>>(q_x, bq, Wq, Wk, Wv, q_ws, k_ws, vt_ws);
  attn_k<<<512, 256, 0, stream>>>(q_ws, k_ws, vt_ws, bias, o_ws);
  outp_k<<<dim3(64, 4), 256, 0, stream>>>(o_ws, q_x, Wg, Wout, bout, bg, gbias, out);
}